// Round 1
// baseline (2134.038 us; speedup 1.0000x reference)
//
#include <hip/hip_runtime.h>
#include <math.h>

// XFADS: N=32, T=1024, D_OBS=128, D_Z=64, D_U=8, H_ENC=256, H_BW=128, H_DYN=256, D_A=128
#define T_LEN 1024
#define NB 32

__device__ __forceinline__ float softplus_f(float x) {
    // matches jax.nn.softplus = log1p(exp(x)) computed stably
    return fmaxf(x, 0.f) + log1pf(expf(-fabsf(x)));
}

// -------------------------------------------------------------------------
// K1: encoder  h = tanh(y@W1+b1); a = h@W2+b2;
//     apre[t][n][:] = a@bw_wa + bw_b          (backward-scan input, hoisted)
//     preU[t][n][:] = u@dyn_w1[64:72] + dyn_b1 (forward-scan input, hoisted)
// 8 rows (n,t) per block, 256 threads.
// -------------------------------------------------------------------------
__global__ __launch_bounds__(256) void k_encoder(
    const float* __restrict__ y, const float* __restrict__ u,
    const float* __restrict__ w1, const float* __restrict__ b1,
    const float* __restrict__ w2, const float* __restrict__ b2,
    const float* __restrict__ wa, const float* __restrict__ bb,
    const float* __restrict__ dynw1, const float* __restrict__ dynb1,
    float* __restrict__ apre, float* __restrict__ preU)
{
    __shared__ float ly[8][128];
    __shared__ float lh[8][256];
    __shared__ float la[8][128];
    __shared__ float lu[8][8];
    const int tid = threadIdx.x;
    const int row0 = blockIdx.x * 8;   // rows in (n*T + t) order (y layout)

    // load 8 y rows (contiguous 1024 floats) + 8 u rows (contiguous 64 floats)
    ((float4*)&ly[0][0])[tid] = ((const float4*)(y + (size_t)row0 * 128))[tid];
    if (tid < 16)
        ((float4*)&lu[0][0])[tid] = ((const float4*)(u + (size_t)row0 * 8))[tid];
    __syncthreads();

    // stage 1: h[r][j] = tanh(y[r]@W1[:,j] + b1[j]),  j = tid (0..255)
    {
        float acc[8] = {0,0,0,0,0,0,0,0};
        for (int i = 0; i < 128; i += 4) {
            float w0 = w1[(i+0)*256 + tid];
            float w1v = w1[(i+1)*256 + tid];
            float w2v = w1[(i+2)*256 + tid];
            float w3 = w1[(i+3)*256 + tid];
            #pragma unroll
            for (int r = 0; r < 8; ++r) {
                float4 yv = *(const float4*)&ly[r][i];
                acc[r] += yv.x*w0 + yv.y*w1v + yv.z*w2v + yv.w*w3;
            }
        }
        float bias = b1[tid];
        #pragma unroll
        for (int r = 0; r < 8; ++r) lh[r][tid] = tanhf(acc[r] + bias);
    }
    __syncthreads();

    // stage 2: a[r][d] = h[r]@W2[:,d] + b2[d].  d = tid&127, 4 rows/thread.
    {
        const int d = tid & 127, rh = tid >> 7;
        float acc[4] = {0,0,0,0};
        for (int i = 0; i < 256; i += 4) {
            float w0 = w2[(i+0)*128 + d];
            float w1v = w2[(i+1)*128 + d];
            float w2v = w2[(i+2)*128 + d];
            float w3 = w2[(i+3)*128 + d];
            #pragma unroll
            for (int q = 0; q < 4; ++q) {
                float4 hv = *(const float4*)&lh[rh*4+q][i];
                acc[q] += hv.x*w0 + hv.y*w1v + hv.z*w2v + hv.w*w3;
            }
        }
        float bias = b2[d];
        #pragma unroll
        for (int q = 0; q < 4; ++q) la[rh*4+q][d] = acc[q] + bias;
    }
    __syncthreads();

    // stage 3: apre[r][j] = a[r]@wa[:,j] + bb[j]
    {
        const int j = tid & 127, rh = tid >> 7;
        float acc[4] = {0,0,0,0};
        for (int i = 0; i < 128; i += 4) {
            float w0 = wa[(i+0)*128 + j];
            float w1v = wa[(i+1)*128 + j];
            float w2v = wa[(i+2)*128 + j];
            float w3 = wa[(i+3)*128 + j];
            #pragma unroll
            for (int q = 0; q < 4; ++q) {
                float4 av = *(const float4*)&la[rh*4+q][i];
                acc[q] += av.x*w0 + av.y*w1v + av.z*w2v + av.w*w3;
            }
        }
        float bias = bb[j];
        #pragma unroll
        for (int q = 0; q < 4; ++q) {
            int rn = row0 + rh*4 + q;
            int n = rn >> 10, t = rn & 1023;
            apre[((size_t)t*NB + n)*128 + j] = acc[q] + bias;
        }
    }

    // stage 4: preU[r][k] = u[r]@dyn_w1[64:72, k] + dyn_b1[k],  k = tid
    {
        float wu[8];
        #pragma unroll
        for (int c = 0; c < 8; ++c) wu[c] = dynw1[(64 + c)*256 + tid];
        float bias = dynb1[tid];
        #pragma unroll
        for (int r = 0; r < 8; ++r) {
            float acc = bias;
            #pragma unroll
            for (int c = 0; c < 8; ++c) acc += lu[r][c] * wu[c];
            int rn = row0 + r;
            int n = rn >> 10, t = rn & 1023;
            preU[((size_t)t*NB + n)*256 + tid] = acc;
        }
    }
}

// -------------------------------------------------------------------------
// K2: backward RNN scan. One block per batch n, 256 threads.
// hcell_t = tanh(apre[t] + h_{t+1} @ Wh);   h_T = 0.
// Thread (j = tid&127, half = tid>>7) accumulates half the dot product;
// Wh column half held in 64 VGPRs. h double-buffered in LDS.
// -------------------------------------------------------------------------
__global__ __launch_bounds__(256) void k_bwscan(
    const float* __restrict__ apre, const float* __restrict__ wh,
    float* __restrict__ hcell)
{
    const int n = blockIdx.x;
    const int tid = threadIdx.x;
    const int j = tid & 127, half = tid >> 7;
    __shared__ float h[2][128];
    __shared__ float red[128];

    float wcol[64];
    #pragma unroll
    for (int i = 0; i < 64; ++i) wcol[i] = wh[(half*64 + i)*128 + j];
    if (tid < 128) h[0][tid] = 0.f;
    __syncthreads();

    int cur = 0;
    float ap_cur = apre[((size_t)1023*NB + n)*128 + j];
    for (int t = 1023; t >= 0; --t) {
        // prefetch next step's apre (hides L2/L3 latency off the serial path)
        float ap_next = 0.f;
        if (t > 0) ap_next = apre[((size_t)(t-1)*NB + n)*128 + j];

        float a0=0.f, a1=0.f, a2=0.f, a3=0.f;
        const float* hb = &h[cur][half*64];
        #pragma unroll
        for (int i = 0; i < 64; i += 4) {
            float4 hv = *(const float4*)&hb[i];
            a0 += hv.x * wcol[i+0];
            a1 += hv.y * wcol[i+1];
            a2 += hv.z * wcol[i+2];
            a3 += hv.w * wcol[i+3];
        }
        float acc = (a0+a1) + (a2+a3);
        if (half == 1) red[j] = acc;        // waves 2,3
        __syncthreads();
        if (half == 0) {                    // waves 0,1
            float s = acc + red[j] + ap_cur;
            float hc = tanhf(s);
            h[cur ^ 1][j] = hc;
            hcell[((size_t)t*NB + n)*128 + j] = hc;
        }
        __syncthreads();
        cur ^= 1;
        ap_cur = ap_next;
    }
}

// -------------------------------------------------------------------------
// K3: b = hcell @ wo + bo; alpha = [b[:64], -softplus(b[64:])]
// 8 rows per block (rows already in [t*NB+n] order).
// -------------------------------------------------------------------------
__global__ __launch_bounds__(256) void k_alpha(
    const float* __restrict__ hcell, const float* __restrict__ wo,
    const float* __restrict__ bo, float* __restrict__ alpha)
{
    __shared__ float lhc[8][128];
    const int tid = threadIdx.x;
    const size_t base = (size_t)blockIdx.x * 8 * 128;
    ((float4*)&lhc[0][0])[tid] = ((const float4*)(hcell + base))[tid];
    __syncthreads();

    const int j = tid & 127, rh = tid >> 7;
    float acc[4] = {0,0,0,0};
    for (int i = 0; i < 128; i += 4) {
        float w0 = wo[(i+0)*128 + j];
        float w1v = wo[(i+1)*128 + j];
        float w2v = wo[(i+2)*128 + j];
        float w3 = wo[(i+3)*128 + j];
        #pragma unroll
        for (int q = 0; q < 4; ++q) {
            float4 hv = *(const float4*)&lhc[rh*4+q][i];
            acc[q] += hv.x*w0 + hv.y*w1v + hv.z*w2v + hv.w*w3;
        }
    }
    float bias = bo[j];
    #pragma unroll
    for (int q = 0; q < 4; ++q) {
        float b = acc[q] + bias;
        float val = (j < 64) ? b : -softplus_f(b);
        alpha[base + (size_t)(rh*4+q)*128 + j] = val;
    }
}

// -------------------------------------------------------------------------
// K4: forward posterior scan. One block per batch n, 256 threads.
// hid = tanh(preU[t] + m @ dyn_w1[:64]);  m_p = hid @ dyn_w2 + b2;
// v_p = v + Q;  e1 = m_p/v_p + alpha1;  e2 = -0.5/v_p + alpha2;
// v_s = -0.5/e2;  m_s = v_s*e1.  Out: [m_s, v_s, m_p, v_p].
// -------------------------------------------------------------------------
__global__ __launch_bounds__(256) void k_fwscan(
    const float* __restrict__ alpha, const float* __restrict__ preU,
    const float* __restrict__ dynw1, const float* __restrict__ dynw2,
    const float* __restrict__ dynb2, const float* __restrict__ qraw,
    const float* __restrict__ m0, const float* __restrict__ v0,
    float* __restrict__ out)
{
    const int n = blockIdx.x;
    const int tid = threadIdx.x;
    const int d = tid & 63, q = tid >> 6;
    __shared__ float lm[2][64];
    __shared__ float lhid[256];
    __shared__ float pred[4][64];

    float w1col[64];  // dyn_w1[i][tid], i<64 (m part)
    #pragma unroll
    for (int i = 0; i < 64; ++i) w1col[i] = dynw1[i*256 + tid];
    float w2col[64];  // dyn_w2[q*64+i][d]
    #pragma unroll
    for (int i = 0; i < 64; ++i) w2col[i] = dynw2[(q*64 + i)*64 + d];

    float Qv = 0.f, b2v = 0.f, vreg = 0.f;
    if (tid < 64) {
        Qv = softplus_f(qraw[tid]);
        b2v = dynb2[tid];
        vreg = v0[tid];
        lm[0][tid] = m0[tid];
    }
    __syncthreads();

    int cur = 0;
    float hpre = preU[(size_t)n * 256 + tid];
    float al1 = 0.f, al2 = 0.f;
    if (tid < 64) {
        al1 = alpha[(size_t)n * 128 + tid];
        al2 = alpha[(size_t)n * 128 + 64 + tid];
    }

    for (int t = 0; t < T_LEN; ++t) {
        // prefetch next step inputs
        float hpre_n = 0.f, al1_n = 0.f, al2_n = 0.f;
        if (t + 1 < T_LEN) {
            hpre_n = preU[((size_t)(t+1)*NB + n)*256 + tid];
            if (tid < 64) {
                al1_n = alpha[((size_t)(t+1)*NB + n)*128 + tid];
                al2_n = alpha[((size_t)(t+1)*NB + n)*128 + 64 + tid];
            }
        }

        // hidden layer: every thread computes one of 256 hiddens
        float a0=0.f, a1=0.f, a2=0.f, a3=0.f;
        #pragma unroll
        for (int i = 0; i < 64; i += 4) {
            float4 mv = *(const float4*)&lm[cur][i];
            a0 += mv.x * w1col[i+0];
            a1 += mv.y * w1col[i+1];
            a2 += mv.z * w1col[i+2];
            a3 += mv.w * w1col[i+3];
        }
        lhid[tid] = tanhf(hpre + (a0+a1) + (a2+a3));
        __syncthreads();

        // output layer: 4 threads per output d, 64-deep partials
        float b0=0.f, b1v=0.f, b2p=0.f, b3=0.f;
        #pragma unroll
        for (int i = 0; i < 64; i += 4) {
            float4 hv = *(const float4*)&lhid[q*64 + i];
            b0  += hv.x * w2col[i+0];
            b1v += hv.y * w2col[i+1];
            b2p += hv.z * w2col[i+2];
            b3  += hv.w * w2col[i+3];
        }
        pred[q][d] = (b0+b1v) + (b2p+b3);
        __syncthreads();

        if (tid < 64) {  // wave 0 only
            float m_p = pred[0][d] + pred[1][d] + pred[2][d] + pred[3][d] + b2v;
            float v_p = vreg + Qv;
            float e1 = m_p / v_p + al1;
            float e2 = -0.5f / v_p + al2;
            float v_s = -0.5f / e2;
            float m_s = v_s * e1;
            vreg = v_s;
            lm[cur ^ 1][d] = m_s;
            size_t ob = ((size_t)n * T_LEN + t) * 256;
            out[ob + d]        = m_s;
            out[ob + 64 + d]   = v_s;
            out[ob + 128 + d]  = m_p;
            out[ob + 192 + d]  = v_p;
        }
        __syncthreads();
        cur ^= 1;
        hpre = hpre_n; al1 = al1_n; al2 = al2_n;
    }
}

// -------------------------------------------------------------------------
extern "C" void kernel_launch(void* const* d_in, const int* in_sizes, int n_in,
                              void* d_out, int out_size, void* d_ws, size_t ws_size,
                              hipStream_t stream) {
    const float* y      = (const float*)d_in[1];
    const float* u      = (const float*)d_in[2];
    const float* enc_w1 = (const float*)d_in[3];
    const float* enc_b1 = (const float*)d_in[4];
    const float* enc_w2 = (const float*)d_in[5];
    const float* enc_b2 = (const float*)d_in[6];
    const float* bw_wa  = (const float*)d_in[7];
    const float* bw_wh  = (const float*)d_in[8];
    const float* bw_b   = (const float*)d_in[9];
    const float* bw_wo  = (const float*)d_in[10];
    const float* bw_bo  = (const float*)d_in[11];
    const float* dyn_w1 = (const float*)d_in[12];
    const float* dyn_b1 = (const float*)d_in[13];
    const float* dyn_w2 = (const float*)d_in[14];
    const float* dyn_b2 = (const float*)d_in[15];
    const float* q_raw  = (const float*)d_in[16];
    const float* m0     = (const float*)d_in[17];
    const float* v0     = (const float*)d_in[18];
    float* out = (float*)d_out;

    // workspace layout (floats): apre/alpha aliased (16MB), hcell (16MB), preU (32MB)
    float* ws = (float*)d_ws;
    float* apre  = ws;                  // [T*NB][128]  — consumed by K2, then reused as alpha
    float* hcell = ws + 4194304;        // [T*NB][128]
    float* alpha = ws;                  // aliases apre (K2 finished before K3 writes)
    float* preU  = ws + 2 * 4194304;    // [T*NB][256]

    k_encoder<<<4096, 256, 0, stream>>>(y, u, enc_w1, enc_b1, enc_w2, enc_b2,
                                        bw_wa, bw_b, dyn_w1, dyn_b1, apre, preU);
    k_bwscan<<<NB, 256, 0, stream>>>(apre, bw_wh, hcell);
    k_alpha<<<4096, 256, 0, stream>>>(hcell, bw_wo, bw_bo, alpha);
    k_fwscan<<<NB, 256, 0, stream>>>(alpha, preU, dyn_w1, dyn_w2, dyn_b2,
                                     q_raw, m0, v0, out);
}

// Round 2
// 1629.088 us; speedup vs baseline: 1.3100x; 1.3100x over previous
//
#include <hip/hip_runtime.h>
#include <math.h>

// XFADS: N=32, T=1024, D_OBS=128, D_Z=64, D_U=8, H_ENC=256, H_BW=128, H_DYN=256, D_A=128
#define T_LEN 1024
#define NB 32

__device__ __forceinline__ float softplus_f(float x) {
    return fmaxf(x, 0.f) + log1pf(expf(-fabsf(x)));
}

// fast tanh: 1 - 2/(1+exp2(2*log2e*x)); exp2/rcp are 1-ulp HW ops.
__device__ __forceinline__ float fast_tanh(float x) {
    float e = __builtin_amdgcn_exp2f(x * 2.88539008177792681472f);
    float r = __builtin_amdgcn_rcpf(1.f + e);
    return 1.f - 2.f * r;
}

// raw barrier: manual lgkmcnt drain, do NOT drain vmcnt (keep global prefetch
// loads in flight across the barrier — the whole point; see m201/T4 pattern)
__device__ __forceinline__ void bar_sync() {
    asm volatile("s_waitcnt lgkmcnt(0)" ::: "memory");
    __builtin_amdgcn_s_barrier();
    asm volatile("" ::: "memory");
}

// -------------------------------------------------------------------------
// K1: encoder  h = tanh(y@W1+b1); a = h@W2+b2;
//     apre[t][n][:] = a@bw_wa + bw_b          (backward-scan input, hoisted)
//     preU[t][n][:] = u@dyn_w1[64:72] + dyn_b1 (forward-scan input, hoisted)
// -------------------------------------------------------------------------
__global__ __launch_bounds__(256) void k_encoder(
    const float* __restrict__ y, const float* __restrict__ u,
    const float* __restrict__ w1, const float* __restrict__ b1,
    const float* __restrict__ w2, const float* __restrict__ b2,
    const float* __restrict__ wa, const float* __restrict__ bb,
    const float* __restrict__ dynw1, const float* __restrict__ dynb1,
    float* __restrict__ apre, float* __restrict__ preU)
{
    __shared__ float ly[8][128];
    __shared__ float lh[8][256];
    __shared__ float la[8][128];
    __shared__ float lu[8][8];
    const int tid = threadIdx.x;
    const int row0 = blockIdx.x * 8;

    ((float4*)&ly[0][0])[tid] = ((const float4*)(y + (size_t)row0 * 128))[tid];
    if (tid < 16)
        ((float4*)&lu[0][0])[tid] = ((const float4*)(u + (size_t)row0 * 8))[tid];
    __syncthreads();

    {
        float acc[8] = {0,0,0,0,0,0,0,0};
        for (int i = 0; i < 128; i += 4) {
            float w0 = w1[(i+0)*256 + tid];
            float w1v = w1[(i+1)*256 + tid];
            float w2v = w1[(i+2)*256 + tid];
            float w3 = w1[(i+3)*256 + tid];
            #pragma unroll
            for (int r = 0; r < 8; ++r) {
                float4 yv = *(const float4*)&ly[r][i];
                acc[r] += yv.x*w0 + yv.y*w1v + yv.z*w2v + yv.w*w3;
            }
        }
        float bias = b1[tid];
        #pragma unroll
        for (int r = 0; r < 8; ++r) lh[r][tid] = fast_tanh(acc[r] + bias);
    }
    __syncthreads();

    {
        const int d = tid & 127, rh = tid >> 7;
        float acc[4] = {0,0,0,0};
        for (int i = 0; i < 256; i += 4) {
            float w0 = w2[(i+0)*128 + d];
            float w1v = w2[(i+1)*128 + d];
            float w2v = w2[(i+2)*128 + d];
            float w3 = w2[(i+3)*128 + d];
            #pragma unroll
            for (int q = 0; q < 4; ++q) {
                float4 hv = *(const float4*)&lh[rh*4+q][i];
                acc[q] += hv.x*w0 + hv.y*w1v + hv.z*w2v + hv.w*w3;
            }
        }
        float bias = b2[d];
        #pragma unroll
        for (int q = 0; q < 4; ++q) la[rh*4+q][d] = acc[q] + bias;
    }
    __syncthreads();

    {
        const int j = tid & 127, rh = tid >> 7;
        float acc[4] = {0,0,0,0};
        for (int i = 0; i < 128; i += 4) {
            float w0 = wa[(i+0)*128 + j];
            float w1v = wa[(i+1)*128 + j];
            float w2v = wa[(i+2)*128 + j];
            float w3 = wa[(i+3)*128 + j];
            #pragma unroll
            for (int q = 0; q < 4; ++q) {
                float4 av = *(const float4*)&la[rh*4+q][i];
                acc[q] += av.x*w0 + av.y*w1v + av.z*w2v + av.w*w3;
            }
        }
        float bias = bb[j];
        #pragma unroll
        for (int q = 0; q < 4; ++q) {
            int rn = row0 + rh*4 + q;
            int n = rn >> 10, t = rn & 1023;
            apre[((size_t)t*NB + n)*128 + j] = acc[q] + bias;
        }
    }

    {
        float wu[8];
        #pragma unroll
        for (int c = 0; c < 8; ++c) wu[c] = dynw1[(64 + c)*256 + tid];
        float bias = dynb1[tid];
        #pragma unroll
        for (int r = 0; r < 8; ++r) {
            float acc = bias;
            #pragma unroll
            for (int c = 0; c < 8; ++c) acc += lu[r][c] * wu[c];
            int rn = row0 + r;
            int n = rn >> 10, t = rn & 1023;
            preU[((size_t)t*NB + n)*256 + tid] = acc;
        }
    }
}

// -------------------------------------------------------------------------
// K2: backward RNN scan. 1 block/batch, 256 threads.
// thread (j = tid>>1, p = tid&1): 64-MAC partial of h@Wh column j,
// shfl_xor(1) pair-reduce -> ONE barrier per step. Prefetch distance 2.
// -------------------------------------------------------------------------
__global__ __launch_bounds__(256, 1) void k_bwscan(
    const float* __restrict__ apre, const float* __restrict__ wh,
    float* __restrict__ hcell)
{
    const int n = blockIdx.x;
    const int tid = threadIdx.x;
    const int j = tid >> 1, p = tid & 1;
    __shared__ float h[2][128];

    float wcol[64];
    #pragma unroll
    for (int i = 0; i < 64; ++i) wcol[i] = wh[(p*64 + i)*128 + j];
    if (tid < 128) h[0][tid] = 0.f;
    __syncthreads();

    // prefetch ring, distance 2
    float apA = apre[((size_t)1023*NB + n)*128 + j];
    float apB = apre[((size_t)1022*NB + n)*128 + j];
    int cur = 0;

    for (int t = 1023; t > 0; t -= 2) {
        // ---- step t (consumes apA) ----
        float apn0 = 0.f;
        if (t - 2 >= 0) apn0 = apre[((size_t)(t-2)*NB + n)*128 + j];
        {
            const float* hb = &h[cur][p*64];
            float a0=0.f, a1=0.f, a2=0.f, a3=0.f;
            #pragma unroll
            for (int i = 0; i < 64; i += 4) {
                float4 hv = *(const float4*)&hb[i];
                a0 += hv.x * wcol[i+0];
                a1 += hv.y * wcol[i+1];
                a2 += hv.z * wcol[i+2];
                a3 += hv.w * wcol[i+3];
            }
            float acc = (a0+a1) + (a2+a3);
            acc += __shfl_xor(acc, 1);
            float hc = fast_tanh(acc + apA);
            if (p == 0) {
                h[cur ^ 1][j] = hc;
                hcell[((size_t)t*NB + n)*128 + j] = hc;
            }
            bar_sync();
        }
        cur ^= 1;
        // ---- step t-1 (consumes apB) ----
        float apn1 = 0.f;
        if (t - 3 >= 0) apn1 = apre[((size_t)(t-3)*NB + n)*128 + j];
        {
            const float* hb = &h[cur][p*64];
            float a0=0.f, a1=0.f, a2=0.f, a3=0.f;
            #pragma unroll
            for (int i = 0; i < 64; i += 4) {
                float4 hv = *(const float4*)&hb[i];
                a0 += hv.x * wcol[i+0];
                a1 += hv.y * wcol[i+1];
                a2 += hv.z * wcol[i+2];
                a3 += hv.w * wcol[i+3];
            }
            float acc = (a0+a1) + (a2+a3);
            acc += __shfl_xor(acc, 1);
            float hc = fast_tanh(acc + apB);
            if (p == 0) {
                h[cur ^ 1][j] = hc;
                hcell[((size_t)(t-1)*NB + n)*128 + j] = hc;
            }
            bar_sync();
        }
        cur ^= 1;
        apA = apn0; apB = apn1;
    }
}

// -------------------------------------------------------------------------
// K3: b = hcell @ wo + bo; alpha = [b[:64], -softplus(b[64:])]
// -------------------------------------------------------------------------
__global__ __launch_bounds__(256) void k_alpha(
    const float* __restrict__ hcell, const float* __restrict__ wo,
    const float* __restrict__ bo, float* __restrict__ alpha)
{
    __shared__ float lhc[8][128];
    const int tid = threadIdx.x;
    const size_t base = (size_t)blockIdx.x * 8 * 128;
    ((float4*)&lhc[0][0])[tid] = ((const float4*)(hcell + base))[tid];
    __syncthreads();

    const int j = tid & 127, rh = tid >> 7;
    float acc[4] = {0,0,0,0};
    for (int i = 0; i < 128; i += 4) {
        float w0 = wo[(i+0)*128 + j];
        float w1v = wo[(i+1)*128 + j];
        float w2v = wo[(i+2)*128 + j];
        float w3 = wo[(i+3)*128 + j];
        #pragma unroll
        for (int q = 0; q < 4; ++q) {
            float4 hv = *(const float4*)&lhc[rh*4+q][i];
            acc[q] += hv.x*w0 + hv.y*w1v + hv.z*w2v + hv.w*w3;
        }
    }
    float bias = bo[j];
    #pragma unroll
    for (int q = 0; q < 4; ++q) {
        float b = acc[q] + bias;
        float val = (j < 64) ? b : -softplus_f(b);
        alpha[base + (size_t)(rh*4+q)*128 + j] = val;
    }
}

// -------------------------------------------------------------------------
// K4: forward posterior scan. 1 block/batch, 256 threads, 2 barriers/step.
// L1: thread tid -> hid[tid] (full 64-dot, lm broadcast reads).
// L2: thread (d = tid>>2, p = tid&3) -> quarter-partial of output d,
//     shfl_xor(1)+(2) intra-wave reduce; update replicated per lane-group;
//     v kept in registers (replicated x4).
// -------------------------------------------------------------------------
#define LHID_IDX(h) ((h) + 8*((h) >> 6))   // pad 8 floats per 64 -> banks spread

__global__ __launch_bounds__(256, 1) void k_fwscan(
    const float* __restrict__ alpha, const float* __restrict__ preU,
    const float* __restrict__ dynw1, const float* __restrict__ dynw2,
    const float* __restrict__ dynb2, const float* __restrict__ qraw,
    const float* __restrict__ m0, const float* __restrict__ v0,
    float* __restrict__ out)
{
    const int n = blockIdx.x;
    const int tid = threadIdx.x;
    const int d = tid >> 2, p = tid & 3;
    __shared__ float lm[2][64];
    __shared__ float lhid[280];

    float w1col[64];            // dyn_w1[i][tid], i<64
    #pragma unroll
    for (int i = 0; i < 64; ++i) w1col[i] = dynw1[i*256 + tid];
    float w2p[64];              // dyn_w2[64p+i][d]
    #pragma unroll
    for (int i = 0; i < 64; ++i) w2p[i] = dynw2[(p*64 + i)*64 + d];

    const float Qv  = softplus_f(qraw[d]);
    const float b2v = dynb2[d];
    float vreg = v0[d];
    if (tid < 64) lm[0][tid] = m0[tid];

    float hpre = preU[(size_t)n * 256 + tid];
    float al1 = alpha[(size_t)n * 128 + d];
    float al2 = alpha[(size_t)n * 128 + 64 + d];
    __syncthreads();

    int cur = 0;
    for (int t = 0; t < T_LEN; ++t) {
        // prefetch next step's inputs (stay in flight across raw barriers)
        float hpre_n = 0.f, al1_n = 0.f, al2_n = 0.f;
        if (t + 1 < T_LEN) {
            hpre_n = preU[((size_t)(t+1)*NB + n)*256 + tid];
            al1_n  = alpha[((size_t)(t+1)*NB + n)*128 + d];
            al2_n  = alpha[((size_t)(t+1)*NB + n)*128 + 64 + d];
        }

        // L1: hid[tid] = tanh(hpre + m @ w1col)  (lm reads are broadcasts)
        {
            float a0=0.f, a1=0.f, a2=0.f, a3=0.f;
            #pragma unroll
            for (int i = 0; i < 64; i += 4) {
                float4 mv = *(const float4*)&lm[cur][i];
                a0 += mv.x * w1col[i+0];
                a1 += mv.y * w1col[i+1];
                a2 += mv.z * w1col[i+2];
                a3 += mv.w * w1col[i+3];
            }
            lhid[LHID_IDX(tid)] = fast_tanh(hpre + (a0+a1) + (a2+a3));
        }
        bar_sync();

        // L2: quarter-dot + intra-wave reduce, then replicated update
        {
            const float* hb = &lhid[LHID_IDX(p*64)];
            float b0=0.f, b1v=0.f, b2p=0.f, b3=0.f;
            #pragma unroll
            for (int i = 0; i < 64; i += 4) {
                float4 hv = *(const float4*)&hb[i];
                b0  += hv.x * w2p[i+0];
                b1v += hv.y * w2p[i+1];
                b2p += hv.z * w2p[i+2];
                b3  += hv.w * w2p[i+3];
            }
            float acc = (b0+b1v) + (b2p+b3);
            acc += __shfl_xor(acc, 1);
            acc += __shfl_xor(acc, 2);

            float m_p = acc + b2v;
            float v_p = vreg + Qv;
            float rvp = __builtin_amdgcn_rcpf(v_p);
            float e1 = m_p * rvp + al1;
            float e2 = al2 - 0.5f * rvp;
            float v_s = -0.5f * __builtin_amdgcn_rcpf(e2);
            float m_s = v_s * e1;
            vreg = v_s;
            if (p == 0) lm[cur ^ 1][d] = m_s;

            size_t ob = ((size_t)n * T_LEN + t) * 256;
            float val = (p == 0) ? m_s : (p == 1) ? v_s : (p == 2) ? m_p : v_p;
            out[ob + (size_t)p*64 + d] = val;
        }
        bar_sync();
        cur ^= 1;
        hpre = hpre_n; al1 = al1_n; al2 = al2_n;
    }
}

// -------------------------------------------------------------------------
extern "C" void kernel_launch(void* const* d_in, const int* in_sizes, int n_in,
                              void* d_out, int out_size, void* d_ws, size_t ws_size,
                              hipStream_t stream) {
    const float* y      = (const float*)d_in[1];
    const float* u      = (const float*)d_in[2];
    const float* enc_w1 = (const float*)d_in[3];
    const float* enc_b1 = (const float*)d_in[4];
    const float* enc_w2 = (const float*)d_in[5];
    const float* enc_b2 = (const float*)d_in[6];
    const float* bw_wa  = (const float*)d_in[7];
    const float* bw_wh  = (const float*)d_in[8];
    const float* bw_b   = (const float*)d_in[9];
    const float* bw_wo  = (const float*)d_in[10];
    const float* bw_bo  = (const float*)d_in[11];
    const float* dyn_w1 = (const float*)d_in[12];
    const float* dyn_b1 = (const float*)d_in[13];
    const float* dyn_w2 = (const float*)d_in[14];
    const float* dyn_b2 = (const float*)d_in[15];
    const float* q_raw  = (const float*)d_in[16];
    const float* m0     = (const float*)d_in[17];
    const float* v0     = (const float*)d_in[18];
    float* out = (float*)d_out;

    float* ws = (float*)d_ws;
    float* apre  = ws;                  // [T*NB][128]
    float* hcell = ws + 4194304;        // [T*NB][128]
    float* alpha = ws;                  // aliases apre (apre dead after K2)
    float* preU  = ws + 2 * 4194304;    // [T*NB][256]

    k_encoder<<<4096, 256, 0, stream>>>(y, u, enc_w1, enc_b1, enc_w2, enc_b2,
                                        bw_wa, bw_b, dyn_w1, dyn_b1, apre, preU);
    k_bwscan<<<NB, 256, 0, stream>>>(apre, bw_wh, hcell);
    k_alpha<<<4096, 256, 0, stream>>>(hcell, bw_wo, bw_bo, alpha);
    k_fwscan<<<NB, 256, 0, stream>>>(alpha, preU, dyn_w1, dyn_w2, dyn_b2,
                                     q_raw, m0, v0, out);
}